// Round 2
// baseline (354.485 us; speedup 1.0000x reference)
//
#include <hip/hip_runtime.h>

// Fokker-Planck 2D explicit update on MI355X (gfx950)
// f' = max(f + dt * (-div(A f) + 0.5 * div^2(B f)), 0)
// Shapes: f [32,512,512], dt [32], A [32,2,512,512], B [32,3,512,512], all fp32.

constexpr int NXc = 512;
constexpr int NYc = 512;
constexpr int NBc = 32;

__global__ __launch_bounds__(256) void fp2d_kernel(
    const float* __restrict__ f,
    const float* __restrict__ dt,
    const float* __restrict__ A,
    const float* __restrict__ Bm,
    float* __restrict__ out)
{
    const int gid = blockIdx.x * 256 + threadIdx.x;
    const int y = gid & (NYc - 1);
    const int x = (gid >> 9) & (NXc - 1);
    const int b = gid >> 18;

    const size_t plane = (size_t)NXc * NYc;
    const float* fb = f  + (size_t)b * plane;
    const float* A0 = A  + (size_t)b * 2 * plane;
    const float* A1 = A0 + plane;
    const float* B0 = Bm + (size_t)b * 3 * plane;
    const float* B1 = B0 + plane;
    const float* B2 = B1 + plane;

    // ---------- first-derivative 3-point stencil along x ----------
    // interior: indices {x-1, x, x+1}, weights {-0.5, 0, 0.5}
    int xa, xb_, xc; float wxa, wxb, wxc;
    if (x == 0) {
        xa = 0;       xb_ = 1;       xc = 2;
        wxa = -1.5f;  wxb =  2.0f;   wxc = -0.5f;
    } else if (x == NXc - 1) {
        xa = NXc - 1; xb_ = NXc - 2; xc = NXc - 3;
        wxa =  1.5f;  wxb = -2.0f;   wxc =  0.5f;
    } else {
        xa = x - 1;   xb_ = x;       xc = x + 1;
        wxa = -0.5f;  wxb =  0.0f;   wxc =  0.5f;
    }

    // ---------- first-derivative 3-point stencil along y ----------
    int ya, yb_, yc; float wya, wyb, wyc;
    if (y == 0) {
        ya = 0;       yb_ = 1;       yc = 2;
        wya = -1.5f;  wyb =  2.0f;   wyc = -0.5f;
    } else if (y == NYc - 1) {
        ya = NYc - 1; yb_ = NYc - 2; yc = NYc - 3;
        wya =  1.5f;  wyb = -2.0f;   wyc =  0.5f;
    } else {
        ya = y - 1;   yb_ = y;       yc = y + 1;
        wya = -0.5f;  wyb =  0.0f;   wyc =  0.5f;
    }

    // ---------- second-derivative 4-point stencil along x ----------
    // interior: {x-1, x, x+1, x} weights {1, -2, 1, 0}
    int u0, u1, u2, u3; float v0, v1, v2, v3;
    if (x == 0) {
        u0 = 0; u1 = 1; u2 = 2; u3 = 3;
        v0 = 2.0f; v1 = -5.0f; v2 = 4.0f; v3 = -1.0f;
    } else if (x == NXc - 1) {
        u0 = NXc - 1; u1 = NXc - 2; u2 = NXc - 3; u3 = NXc - 4;
        v0 = 2.0f; v1 = -5.0f; v2 = 4.0f; v3 = -1.0f;
    } else {
        u0 = x - 1; u1 = x; u2 = x + 1; u3 = x;
        v0 = 1.0f; v1 = -2.0f; v2 = 1.0f; v3 = 0.0f;
    }

    // ---------- second-derivative 4-point stencil along y ----------
    int s0, s1, s2, s3; float t0, t1, t2, t3;
    if (y == 0) {
        s0 = 0; s1 = 1; s2 = 2; s3 = 3;
        t0 = 2.0f; t1 = -5.0f; t2 = 4.0f; t3 = -1.0f;
    } else if (y == NYc - 1) {
        s0 = NYc - 1; s1 = NYc - 2; s2 = NYc - 3; s3 = NYc - 4;
        t0 = 2.0f; t1 = -5.0f; t2 = 4.0f; t3 = -1.0f;
    } else {
        s0 = y - 1; s1 = y; s2 = y + 1; s3 = y;
        t0 = 1.0f; t1 = -2.0f; t2 = 1.0f; t3 = 0.0f;
    }

    // ---------- gradv = Dx(A0*f) + Dy(A1*f) ----------
    float gradv = 0.0f;
    gradv = fmaf(wxa, A0[(size_t)xa * NYc + y] * fb[(size_t)xa * NYc + y], gradv);
    gradv = fmaf(wxb, A0[(size_t)xb_ * NYc + y] * fb[(size_t)xb_ * NYc + y], gradv);
    gradv = fmaf(wxc, A0[(size_t)xc * NYc + y] * fb[(size_t)xc * NYc + y], gradv);
    gradv = fmaf(wya, A1[(size_t)x * NYc + ya] * fb[(size_t)x * NYc + ya], gradv);
    gradv = fmaf(wyb, A1[(size_t)x * NYc + yb_] * fb[(size_t)x * NYc + yb_], gradv);
    gradv = fmaf(wyc, A1[(size_t)x * NYc + yc] * fb[(size_t)x * NYc + yc], gradv);

    // ---------- gradvv = Dxx(B0*f) + Dyy(B1*f) + 2*DxDy(B2*f) ----------
    float gradvv = 0.0f;
    gradvv = fmaf(v0, B0[(size_t)u0 * NYc + y] * fb[(size_t)u0 * NYc + y], gradvv);
    gradvv = fmaf(v1, B0[(size_t)u1 * NYc + y] * fb[(size_t)u1 * NYc + y], gradvv);
    gradvv = fmaf(v2, B0[(size_t)u2 * NYc + y] * fb[(size_t)u2 * NYc + y], gradvv);
    gradvv = fmaf(v3, B0[(size_t)u3 * NYc + y] * fb[(size_t)u3 * NYc + y], gradvv);

    gradvv = fmaf(t0, B1[(size_t)x * NYc + s0] * fb[(size_t)x * NYc + s0], gradvv);
    gradvv = fmaf(t1, B1[(size_t)x * NYc + s1] * fb[(size_t)x * NYc + s1], gradvv);
    gradvv = fmaf(t2, B1[(size_t)x * NYc + s2] * fb[(size_t)x * NYc + s2], gradvv);
    gradvv = fmaf(t3, B1[(size_t)x * NYc + s3] * fb[(size_t)x * NYc + s3], gradvv);

    // cross term: Dx(Dy(B2*f)) computed once, doubled (operators commute).
    // 3x3 product of the two first-derivative stencils; interior middle
    // weights are 0 so only 4 of 9 terms contribute there.
    float cross = 0.0f;
    {
        // row xa
        float r = 0.0f;
        r = fmaf(wya, B2[(size_t)xa * NYc + ya] * fb[(size_t)xa * NYc + ya], r);
        r = fmaf(wyb, B2[(size_t)xa * NYc + yb_] * fb[(size_t)xa * NYc + yb_], r);
        r = fmaf(wyc, B2[(size_t)xa * NYc + yc] * fb[(size_t)xa * NYc + yc], r);
        cross = fmaf(wxa, r, cross);
    }
    {
        // row xb_
        float r = 0.0f;
        r = fmaf(wya, B2[(size_t)xb_ * NYc + ya] * fb[(size_t)xb_ * NYc + ya], r);
        r = fmaf(wyb, B2[(size_t)xb_ * NYc + yb_] * fb[(size_t)xb_ * NYc + yb_], r);
        r = fmaf(wyc, B2[(size_t)xb_ * NYc + yc] * fb[(size_t)xb_ * NYc + yc], r);
        cross = fmaf(wxb, r, cross);
    }
    {
        // row xc
        float r = 0.0f;
        r = fmaf(wya, B2[(size_t)xc * NYc + ya] * fb[(size_t)xc * NYc + ya], r);
        r = fmaf(wyb, B2[(size_t)xc * NYc + yb_] * fb[(size_t)xc * NYc + yb_], r);
        r = fmaf(wyc, B2[(size_t)xc * NYc + yc] * fb[(size_t)xc * NYc + yc], r);
        cross = fmaf(wxc, r, cross);
    }
    gradvv = fmaf(2.0f, cross, gradvv);

    const float fc = fb[(size_t)x * NYc + y];
    const float df = -gradv + 0.5f * gradvv;
    const float val = fmaf(df, dt[b], fc);
    out[gid] = fmaxf(val, 0.0f);
}

extern "C" void kernel_launch(void* const* d_in, const int* in_sizes, int n_in,
                              void* d_out, int out_size, void* d_ws, size_t ws_size,
                              hipStream_t stream) {
    const float* f  = (const float*)d_in[0];
    const float* dt = (const float*)d_in[1];
    const float* A  = (const float*)d_in[2];
    const float* Bm = (const float*)d_in[3];
    float* out = (float*)d_out;

    const int total = NBc * NXc * NYc;         // 8388608
    const int blocks = total / 256;            // 32768
    fp2d_kernel<<<blocks, 256, 0, stream>>>(f, dt, A, Bm, out);
}

// Round 5
// 238.546 us; speedup vs baseline: 1.4860x; 1.4860x over previous
//
#include <hip/hip_runtime.h>

// Fokker-Planck 2D explicit update on MI355X (gfx950), round 2:
// 4 outputs per thread along y, all operands loaded as aligned float4
// (+2 edge scalars per y-window). Block = 1 row (128 thr), x/b wave-uniform.

constexpr int NXc = 512;
constexpr int NYc = 512;
constexpr int NBc = 32;

struct Win { float m1, v0, v1, v2, v3, p4; };  // product window y4-1 .. y4+4

__device__ __forceinline__ float4 mul4(float4 p, float4 q) {
    float4 r; r.x = p.x*q.x; r.y = p.y*q.y; r.z = p.z*q.z; r.w = p.w*q.w; return r;
}
__device__ __forceinline__ float4 fma4s(float s, float4 p, float4 acc) {
    acc.x = fmaf(s, p.x, acc.x); acc.y = fmaf(s, p.y, acc.y);
    acc.z = fmaf(s, p.z, acc.z); acc.w = fmaf(s, p.w, acc.w); return acc;
}
__device__ __forceinline__ float4 add4(float4 a, float4 b) {
    float4 r; r.x = a.x+b.x; r.y = a.y+b.y; r.z = a.z+b.z; r.w = a.w+b.w; return r;
}

__device__ __forceinline__ Win mkwin(float4 a, float am1, float ap4,
                                     float4 fv, float fm1, float fp4) {
    Win w;
    w.m1 = am1 * fm1;
    w.v0 = a.x * fv.x; w.v1 = a.y * fv.y; w.v2 = a.z * fv.z; w.v3 = a.w * fv.w;
    w.p4 = ap4 * fp4;
    return w;
}

// first derivative along y for the 4 outputs of this thread
__device__ __forceinline__ float4 dy4(const Win& w, bool atY0, bool atYN) {
    float4 r;
    r.x = atY0 ? (-1.5f*w.v0 + 2.0f*w.v1 - 0.5f*w.v2) : 0.5f*(w.v1 - w.m1);
    r.y = 0.5f*(w.v2 - w.v0);
    r.z = 0.5f*(w.v3 - w.v1);
    r.w = atYN ? (1.5f*w.v3 - 2.0f*w.v2 + 0.5f*w.v1) : 0.5f*(w.p4 - w.v2);
    return r;
}
// second derivative along y
__device__ __forceinline__ float4 dyy4(const Win& w, bool atY0, bool atYN) {
    float4 r;
    r.x = atY0 ? (2.0f*w.v0 - 5.0f*w.v1 + 4.0f*w.v2 - w.v3) : (w.v1 - 2.0f*w.v0 + w.m1);
    r.y = w.v2 - 2.0f*w.v1 + w.v0;
    r.z = w.v3 - 2.0f*w.v2 + w.v1;
    r.w = atYN ? (2.0f*w.v3 - 5.0f*w.v2 + 4.0f*w.v1 - w.v0) : (w.p4 - 2.0f*w.v3 + w.v2);
    return r;
}

__global__ __launch_bounds__(128) void fp2d_kernel(
    const float* __restrict__ f,
    const float* __restrict__ dt,
    const float* __restrict__ A,
    const float* __restrict__ Bm,
    float* __restrict__ out)
{
    const int x  = blockIdx.x & (NXc - 1);   // wave-uniform
    const int b  = blockIdx.x >> 9;          // wave-uniform
    const int y4 = threadIdx.x << 2;         // 0..508, 16B aligned

    const bool atY0 = (y4 == 0);
    const bool atYN = (y4 == NYc - 4);
    const int ym1 = atY0 ? 0 : y4 - 1;        // clamped; unused value at edges
    const int yp4 = atYN ? NYc - 1 : y4 + 4;  // clamped; unused value at edges

    const size_t plane = (size_t)NXc * NYc;
    const float* fb = f  + (size_t)b * plane;
    const float* A0 = A  + (size_t)b * 2 * plane;
    const float* A1 = A0 + plane;
    const float* B0 = Bm + (size_t)b * 3 * plane;
    const float* B1 = B0 + plane;
    const float* B2 = B1 + plane;

    // ----- x-direction stencils (wave-uniform selection) -----
    // 1st deriv: rows xa,xb_,xc with weights wxa,wxb,wxc
    // 2nd deriv: rows xa,xb_,xc,u3 with weights v0..v3
    int xa, xb_, xc, u3; float wxa, wxb, wxc, v0, v1, v2, v3;
    if (x == 0) {
        xa = 0; xb_ = 1; xc = 2; u3 = 3;
        wxa = -1.5f; wxb = 2.0f; wxc = -0.5f;
        v0 = 2.0f; v1 = -5.0f; v2 = 4.0f; v3 = -1.0f;
    } else if (x == NXc - 1) {
        xa = NXc - 1; xb_ = NXc - 2; xc = NXc - 3; u3 = NXc - 4;
        wxa = 1.5f; wxb = -2.0f; wxc = 0.5f;
        v0 = 2.0f; v1 = -5.0f; v2 = 4.0f; v3 = -1.0f;
    } else {
        xa = x - 1; xb_ = x; xc = x + 1; u3 = x;
        wxa = -0.5f; wxb = 0.0f; wxc = 0.5f;
        v0 = 1.0f; v1 = -2.0f; v2 = 1.0f; v3 = 0.0f;
    }
    const bool xInt = (x > 0) && (x < NXc - 1);

    auto ld4 = [](const float* p, int row, int col) -> float4 {
        return *reinterpret_cast<const float4*>(p + (size_t)row * NYc + col);
    };
    auto ld1 = [](const float* p, int row, int col) -> float {
        return p[(size_t)row * NYc + col];
    };

    // ----- loads (all float4 except y-window edge scalars) -----
    float4 f_a = ld4(fb, xa, y4);  float fam = ld1(fb, xa, ym1), fap = ld1(fb, xa, yp4);
    float4 f_b = ld4(fb, xb_, y4); float fbm = ld1(fb, xb_, ym1), fbp = ld1(fb, xb_, yp4);
    float4 f_c = ld4(fb, xc, y4);  float fcm = ld1(fb, xc, ym1), fcp = ld1(fb, xc, yp4);
    float4 f_u = ld4(fb, u3, y4);

    // center row (row x): interior -> xb_, boundary -> xa  (register select, uniform)
    float4 fX = xInt ? f_b : f_a;
    float  fXm = xInt ? fbm : fam;
    float  fXp = xInt ? fbp : fap;

    float4 a0a = ld4(A0, xa, y4), a0b = ld4(A0, xb_, y4), a0c = ld4(A0, xc, y4);
    float4 a1x = ld4(A1, x,  y4); float a1m = ld1(A1, x, ym1), a1p = ld1(A1, x, yp4);

    float4 b0a = ld4(B0, xa, y4), b0b = ld4(B0, xb_, y4), b0c = ld4(B0, xc, y4), b0u = ld4(B0, u3, y4);
    float4 b1x = ld4(B1, x,  y4); float b1m = ld1(B1, x, ym1), b1p = ld1(B1, x, yp4);

    float4 b2a = ld4(B2, xa, y4);  float b2am = ld1(B2, xa, ym1), b2ap = ld1(B2, xa, yp4);
    float4 b2b = ld4(B2, xb_, y4); float b2bm = ld1(B2, xb_, ym1), b2bp = ld1(B2, xb_, yp4);
    float4 b2c = ld4(B2, xc, y4);  float b2cm = ld1(B2, xc, ym1), b2cp = ld1(B2, xc, yp4);

    // ----- gradv = Dx(A0 f) + Dy(A1 f) -----
    float4 zero; zero.x = zero.y = zero.z = zero.w = 0.0f;
    float4 gradv = fma4s(wxa, mul4(a0a, f_a),
                   fma4s(wxb, mul4(a0b, f_b),
                   fma4s(wxc, mul4(a0c, f_c), zero)));
    Win wA1 = mkwin(a1x, a1m, a1p, fX, fXm, fXp);
    gradv = add4(gradv, dy4(wA1, atY0, atYN));

    // ----- gradvv = Dxx(B0 f) + Dyy(B1 f) + 2*DxDy(B2 f) -----
    float4 dxx = fma4s(v0, mul4(b0a, f_a),
                 fma4s(v1, mul4(b0b, f_b),
                 fma4s(v2, mul4(b0c, f_c),
                 fma4s(v3, mul4(b0u, f_u), zero))));

    Win wB1 = mkwin(b1x, b1m, b1p, fX, fXm, fXp);
    float4 dyy = dyy4(wB1, atY0, atYN);

    Win wB2a = mkwin(b2a, b2am, b2ap, f_a, fam, fap);
    Win wB2b = mkwin(b2b, b2bm, b2bp, f_b, fbm, fbp);
    Win wB2c = mkwin(b2c, b2cm, b2cp, f_c, fcm, fcp);
    float4 cross = fma4s(wxa, dy4(wB2a, atY0, atYN),
                   fma4s(wxb, dy4(wB2b, atY0, atYN),
                   fma4s(wxc, dy4(wB2c, atY0, atYN), zero)));

    // df = -gradv + 0.5*(dxx + dyy) + cross   (cross already = one DxDy; doubled via 0.5*2)
    const float dtb = dt[b];
    float4 res;
    {
        float dfx = 0.5f*(dxx.x + dyy.x) + cross.x - gradv.x;
        float dfy = 0.5f*(dxx.y + dyy.y) + cross.y - gradv.y;
        float dfz = 0.5f*(dxx.z + dyy.z) + cross.z - gradv.z;
        float dfw = 0.5f*(dxx.w + dyy.w) + cross.w - gradv.w;
        res.x = fmaxf(fmaf(dfx, dtb, fX.x), 0.0f);
        res.y = fmaxf(fmaf(dfy, dtb, fX.y), 0.0f);
        res.z = fmaxf(fmaf(dfz, dtb, fX.z), 0.0f);
        res.w = fmaxf(fmaf(dfw, dtb, fX.w), 0.0f);
    }

    *reinterpret_cast<float4*>(out + (size_t)b * plane + (size_t)x * NYc + y4) = res;
}

extern "C" void kernel_launch(void* const* d_in, const int* in_sizes, int n_in,
                              void* d_out, int out_size, void* d_ws, size_t ws_size,
                              hipStream_t stream) {
    const float* f  = (const float*)d_in[0];
    const float* dt = (const float*)d_in[1];
    const float* A  = (const float*)d_in[2];
    const float* Bm = (const float*)d_in[3];
    float* out = (float*)d_out;

    const int blocks = NBc * NXc;   // one block per (b, x) row: 16384
    fp2d_kernel<<<blocks, 128, 0, stream>>>(f, dt, A, Bm, out);
}

// Round 6
// 218.490 us; speedup vs baseline: 1.6224x; 1.0918x over previous
//
#include <hip/hip_runtime.h>

// Fokker-Planck 2D explicit update on MI355X (gfx950), round 3:
// - block = 256 threads = 4 waves = 4 consecutive x-rows (one full row per wave)
// - 8 outputs per thread along y (2x float4), all loads aligned float4
// - y-window edge products via intra-wave __shfl (no scalar edge loads)
// f' = max(f + dt * (-div(A f) + 0.5 * div^2(B f)), 0)

constexpr int NXc = 512;
constexpr int NYc = 512;
constexpr int NBc = 32;

struct F8 { float4 lo, hi; };

__device__ __forceinline__ float4 mul4(float4 p, float4 q) {
    float4 r; r.x = p.x*q.x; r.y = p.y*q.y; r.z = p.z*q.z; r.w = p.w*q.w; return r;
}
__device__ __forceinline__ float4 fma4s(float s, float4 p, float4 acc) {
    acc.x = fmaf(s, p.x, acc.x); acc.y = fmaf(s, p.y, acc.y);
    acc.z = fmaf(s, p.z, acc.z); acc.w = fmaf(s, p.w, acc.w); return acc;
}
__device__ __forceinline__ F8 mul8(const F8& a, const F8& b) {
    F8 r; r.lo = mul4(a.lo, b.lo); r.hi = mul4(a.hi, b.hi); return r;
}
__device__ __forceinline__ F8 fma8s(float s, const F8& p, const F8& acc) {
    F8 r; r.lo = fma4s(s, p.lo, acc.lo); r.hi = fma4s(s, p.hi, acc.hi); return r;
}
__device__ __forceinline__ F8 add8(const F8& a, const F8& b) {
    F8 r;
    r.lo.x = a.lo.x+b.lo.x; r.lo.y = a.lo.y+b.lo.y; r.lo.z = a.lo.z+b.lo.z; r.lo.w = a.lo.w+b.lo.w;
    r.hi.x = a.hi.x+b.hi.x; r.hi.y = a.hi.y+b.hi.y; r.hi.z = a.hi.z+b.hi.z; r.hi.w = a.hi.w+b.hi.w;
    return r;
}

__device__ __forceinline__ F8 ld8(const float* __restrict__ p, int row, int y8) {
    const float* q = p + (size_t)row * NYc + y8;
    F8 r;
    r.lo = *reinterpret_cast<const float4*>(q);
    r.hi = *reinterpret_cast<const float4*>(q + 4);
    return r;
}

// product window: 8 per-lane products + neighbors via wave shuffle
struct W8 { float4 lo, hi; float m1, p8; };

__device__ __forceinline__ W8 mkwin8(const F8& a, const F8& f) {
    W8 w;
    w.lo = mul4(a.lo, f.lo);
    w.hi = mul4(a.hi, f.hi);
    w.m1 = __shfl_up(w.hi.w, 1);    // lane L-1's y8+7 == our y8-1 (garbage at lane 0, unused)
    w.p8 = __shfl_down(w.lo.x, 1);  // lane L+1's y8+0 == our y8+8 (garbage at lane 63, unused)
    return w;
}

// first derivative along y for the 8 outputs of this lane
__device__ __forceinline__ F8 dy8(const W8& w, bool atY0, bool atYN) {
    F8 r;
    r.lo.x = atY0 ? (-1.5f*w.lo.x + 2.0f*w.lo.y - 0.5f*w.lo.z) : 0.5f*(w.lo.y - w.m1);
    r.lo.y = 0.5f*(w.lo.z - w.lo.x);
    r.lo.z = 0.5f*(w.lo.w - w.lo.y);
    r.lo.w = 0.5f*(w.hi.x - w.lo.z);
    r.hi.x = 0.5f*(w.hi.y - w.lo.w);
    r.hi.y = 0.5f*(w.hi.z - w.hi.x);
    r.hi.z = 0.5f*(w.hi.w - w.hi.y);
    r.hi.w = atYN ? (1.5f*w.hi.w - 2.0f*w.hi.z + 0.5f*w.hi.y) : 0.5f*(w.p8 - w.hi.z);
    return r;
}
// second derivative along y
__device__ __forceinline__ F8 dyy8(const W8& w, bool atY0, bool atYN) {
    F8 r;
    r.lo.x = atY0 ? (2.0f*w.lo.x - 5.0f*w.lo.y + 4.0f*w.lo.z - w.lo.w)
                  : (w.lo.y - 2.0f*w.lo.x + w.m1);
    r.lo.y = w.lo.z - 2.0f*w.lo.y + w.lo.x;
    r.lo.z = w.lo.w - 2.0f*w.lo.z + w.lo.y;
    r.lo.w = w.hi.x - 2.0f*w.lo.w + w.lo.z;
    r.hi.x = w.hi.y - 2.0f*w.hi.x + w.lo.w;
    r.hi.y = w.hi.z - 2.0f*w.hi.y + w.hi.x;
    r.hi.z = w.hi.w - 2.0f*w.hi.z + w.hi.y;
    r.hi.w = atYN ? (2.0f*w.hi.w - 5.0f*w.hi.z + 4.0f*w.hi.y - w.hi.x)
                  : (w.p8 - 2.0f*w.hi.w + w.hi.z);
    return r;
}

__global__ __launch_bounds__(256) void fp2d_kernel(
    const float* __restrict__ f,
    const float* __restrict__ dt,
    const float* __restrict__ A,
    const float* __restrict__ Bm,
    float* __restrict__ out)
{
    const int tid  = threadIdx.x;
    const int wv   = tid >> 6;            // wave id 0..3 -> row offset
    const int lane = tid & 63;
    const int b    = blockIdx.x >> 7;     // 128 blocks per batch plane
    const int x    = ((blockIdx.x & 127) << 2) + wv;   // wave-uniform
    const int y8   = lane << 3;           // 0..504

    const bool atY0 = (lane == 0);
    const bool atYN = (lane == 63);

    const size_t plane = (size_t)NXc * NYc;
    const float* fb = f  + (size_t)b * plane;
    const float* A0 = A  + (size_t)b * 2 * plane;
    const float* A1 = A0 + plane;
    const float* B0 = Bm + (size_t)b * 3 * plane;
    const float* B1 = B0 + plane;
    const float* B2 = B1 + plane;

    // ----- x-direction stencils (wave-uniform selection) -----
    int xa, xb_, xc, u3; float wxa, wxb, wxc, v0, v1, v2, v3;
    if (x == 0) {
        xa = 0; xb_ = 1; xc = 2; u3 = 3;
        wxa = -1.5f; wxb = 2.0f; wxc = -0.5f;
        v0 = 2.0f; v1 = -5.0f; v2 = 4.0f; v3 = -1.0f;
    } else if (x == NXc - 1) {
        xa = NXc - 1; xb_ = NXc - 2; xc = NXc - 3; u3 = NXc - 4;
        wxa = 1.5f; wxb = -2.0f; wxc = 0.5f;
        v0 = 2.0f; v1 = -5.0f; v2 = 4.0f; v3 = -1.0f;
    } else {
        xa = x - 1; xb_ = x; xc = x + 1; u3 = x;
        wxa = -0.5f; wxb = 0.0f; wxc = 0.5f;
        v0 = 1.0f; v1 = -2.0f; v2 = 1.0f; v3 = 0.0f;
    }
    const bool xInt = (x > 0) && (x < NXc - 1);

    // ----- loads: 16 rows x 2 float4 (interior: u3 row aliases xb_ -> L1 hit) -----
    F8 f_a = ld8(fb, xa, y8);
    F8 f_b = ld8(fb, xb_, y8);
    F8 f_c = ld8(fb, xc, y8);
    F8 f_u = ld8(fb, u3, y8);

    F8 a0a = ld8(A0, xa, y8), a0b = ld8(A0, xb_, y8), a0c = ld8(A0, xc, y8);
    F8 a1x = ld8(A1, x, y8);
    F8 b0a = ld8(B0, xa, y8), b0b = ld8(B0, xb_, y8), b0c = ld8(B0, xc, y8), b0u = ld8(B0, u3, y8);
    F8 b1x = ld8(B1, x, y8);
    F8 b2a = ld8(B2, xa, y8), b2b = ld8(B2, xb_, y8), b2c = ld8(B2, xc, y8);

    // center row for Dy/Dyy/output: interior -> xb_, boundary -> xa (uniform select)
    F8 fX;
    fX.lo = xInt ? f_b.lo : f_a.lo;
    fX.hi = xInt ? f_b.hi : f_a.hi;

    F8 zero8; zero8.lo = make_float4(0.f,0.f,0.f,0.f); zero8.hi = zero8.lo;

    // ----- gradv = Dx(A0 f) + Dy(A1 f) -----
    F8 gradv = fma8s(wxa, mul8(a0a, f_a),
               fma8s(wxb, mul8(a0b, f_b),
               fma8s(wxc, mul8(a0c, f_c), zero8)));
    W8 wA1 = mkwin8(a1x, fX);
    gradv = add8(gradv, dy8(wA1, atY0, atYN));

    // ----- dxx = Dxx(B0 f) -----
    F8 dxx = fma8s(v0, mul8(b0a, f_a),
             fma8s(v1, mul8(b0b, f_b),
             fma8s(v2, mul8(b0c, f_c),
             fma8s(v3, mul8(b0u, f_u), zero8))));

    // ----- dyy = Dyy(B1 f) -----
    W8 wB1 = mkwin8(b1x, fX);
    F8 dyy = dyy8(wB1, atY0, atYN);

    // ----- cross = DxDy(B2 f)  (doubled later via 0.5*2) -----
    W8 wB2a = mkwin8(b2a, f_a);
    W8 wB2b = mkwin8(b2b, f_b);
    W8 wB2c = mkwin8(b2c, f_c);
    F8 cross = fma8s(wxa, dy8(wB2a, atY0, atYN),
               fma8s(wxb, dy8(wB2b, atY0, atYN),
               fma8s(wxc, dy8(wB2c, atY0, atYN), zero8)));

    // ----- combine: df = 0.5*(dxx+dyy) + cross - gradv; out = max(f + dt*df, 0) -----
    const float dtb = dt[b];
    float* orow = out + (size_t)b * plane + (size_t)x * NYc + y8;

    float4 r0, r1;
    r0.x = fmaxf(fmaf(0.5f*(dxx.lo.x + dyy.lo.x) + cross.lo.x - gradv.lo.x, dtb, fX.lo.x), 0.0f);
    r0.y = fmaxf(fmaf(0.5f*(dxx.lo.y + dyy.lo.y) + cross.lo.y - gradv.lo.y, dtb, fX.lo.y), 0.0f);
    r0.z = fmaxf(fmaf(0.5f*(dxx.lo.z + dyy.lo.z) + cross.lo.z - gradv.lo.z, dtb, fX.lo.z), 0.0f);
    r0.w = fmaxf(fmaf(0.5f*(dxx.lo.w + dyy.lo.w) + cross.lo.w - gradv.lo.w, dtb, fX.lo.w), 0.0f);
    r1.x = fmaxf(fmaf(0.5f*(dxx.hi.x + dyy.hi.x) + cross.hi.x - gradv.hi.x, dtb, fX.hi.x), 0.0f);
    r1.y = fmaxf(fmaf(0.5f*(dxx.hi.y + dyy.hi.y) + cross.hi.y - gradv.hi.y, dtb, fX.hi.y), 0.0f);
    r1.z = fmaxf(fmaf(0.5f*(dxx.hi.z + dyy.hi.z) + cross.hi.z - gradv.hi.z, dtb, fX.hi.z), 0.0f);
    r1.w = fmaxf(fmaf(0.5f*(dxx.hi.w + dyy.hi.w) + cross.hi.w - gradv.hi.w, dtb, fX.hi.w), 0.0f);

    *reinterpret_cast<float4*>(orow)     = r0;
    *reinterpret_cast<float4*>(orow + 4) = r1;
}

extern "C" void kernel_launch(void* const* d_in, const int* in_sizes, int n_in,
                              void* d_out, int out_size, void* d_ws, size_t ws_size,
                              hipStream_t stream) {
    const float* f  = (const float*)d_in[0];
    const float* dt = (const float*)d_in[1];
    const float* A  = (const float*)d_in[2];
    const float* Bm = (const float*)d_in[3];
    float* out = (float*)d_out;

    const int blocks = NBc * NXc / 4;   // 4096 blocks: 4 rows per block
    fp2d_kernel<<<blocks, 256, 0, stream>>>(f, dt, A, Bm, out);
}